// Round 6
// baseline (339.712 us; speedup 1.0000x reference)
//
#include <hip/hip_runtime.h>

#define N_PTS 131072
#define TD 4096
#define DD 64
#define KK 1024
#define MARGIN_TH 2e-3f

typedef short bf16x8 __attribute__((ext_vector_type(8)));
typedef float f32x4  __attribute__((ext_vector_type(4)));

__device__ inline unsigned short f2bf(float f) {           // RNE float->bf16
    unsigned u = __float_as_uint(f);
    unsigned r = u + 0x7FFFu + ((u >> 16) & 1u);
    return (unsigned short)(r >> 16);
}
__device__ inline float bf2f(unsigned short h) {
    return __uint_as_float(((unsigned)h) << 16);
}

__device__ inline void gload_lds16(const unsigned short* g, unsigned short* l) {
    __builtin_amdgcn_global_load_lds(
        (const __attribute__((address_space(1))) unsigned int*)g,
        (__attribute__((address_space(3))) unsigned int*)l, 16, 0, 0);
}

// ---------------- K0a: transpose z[B,D,T] -> NEGATED z_hi/z_lo bf16 [N,D] ----------------
// Storing -z lets the screen fold 0.5*||e||^2 into the MFMA accumulator (s = hn + (-z)·e).
__global__ __launch_bounds__(256) void vq_prep(const float* __restrict__ z,
                                               unsigned short* __restrict__ zh,
                                               unsigned short* __restrict__ zl)
{
    __shared__ float tile[64][65];
    const int tid = threadIdx.x;
    const int b = blockIdx.x >> 6;
    const int t0 = (blockIdx.x & 63) * 64;

    const int d = tid >> 2, tq = tid & 3;
#pragma unroll
    for (int it = 0; it < 4; ++it) {
        const int tt = tq * 16 + it * 4;
        const float4 v = *(const float4*)(z + ((size_t)b * DD + d) * TD + t0 + tt);
        tile[d][tt] = v.x; tile[d][tt + 1] = v.y; tile[d][tt + 2] = v.z; tile[d][tt + 3] = v.w;
    }
    __syncthreads();

    const int p = tid >> 2, dg = tid & 3;
    bf16x8 h0, h1, l0, l1;
#pragma unroll
    for (int j = 0; j < 8; ++j) {
        const float v0 = -tile[dg * 16 + j][p];
        const unsigned short a = f2bf(v0);
        h0[j] = (short)a; l0[j] = (short)f2bf(v0 - bf2f(a));
        const float v1 = -tile[dg * 16 + 8 + j][p];
        const unsigned short c = f2bf(v1);
        h1[j] = (short)c; l1[j] = (short)f2bf(v1 - bf2f(c));
    }
    const size_t o = ((size_t)(b * TD + t0 + p)) * DD + dg * 16;
    *(bf16x8*)(zh + o) = h0;
    *(bf16x8*)(zh + o + 8) = h1;
    *(bf16x8*)(zl + o) = l0;
    *(bf16x8*)(zl + o + 8) = l1;
}

// ---------------- K0b: emb -> MFMA-fragment-ordered e_hi/e_lo + fp64-exact half norms ----
// TIGHT layout, 1024 ushorts per 16-code tile (exactly 128 KB per array):
//   code k = t*16+col, dim d = q*8+j (q=0..7, half=q>>2):
//   ef[t*1024 + half*512 + ((q&3)*16 + col)*8 + j]
__global__ __launch_bounds__(256) void vq_eprep(const float* __restrict__ emb,
                                                unsigned short* __restrict__ efh,
                                                unsigned short* __restrict__ efl,
                                                float* __restrict__ halfnorm)
{
    const int k = blockIdx.x * 256 + threadIdx.x;
    if (k >= KK) return;
    const int t = k >> 4, col = k & 15;
    const float* e = emb + (size_t)k * DD;
    double s = 0.0;
#pragma unroll
    for (int d = 0; d < DD; ++d) {
        const float v = e[d];
        const double dv = (double)v;
        s = fma(dv, dv, s);
        const unsigned short h = f2bf(v);
        const int q = d >> 3, j = d & 7;
        const size_t pos = (size_t)t * 1024 + (q >> 2) * 512 + ((q & 3) * 16 + col) * 8 + j;
        efh[pos] = h;
        efl[pos] = f2bf(v - bf2f(h));
    }
    halfnorm[k] = (float)(0.5 * s);
}

// ---------------- K1: MFMA screen v6 — 64 points/wave (2x ILP), LDS-resident quarters ----
// r0 vs r1-r5 evidence: the screen is per-wave latency-bound. v6 doubles independent
// MFMA work per wave: each wave owns 4 point-tiles (A in 64 VGPR, loaded once); per
// code-tile the SAME 4 ds_read_b128 + 1 LDS hn read feed 24 MFMAs in 8 independent
// chains. hn lives in LDS (no vm ops in the sweep at all). 256 thr x 512 blocks,
// 68 KB LDS -> 2 blocks/CU. launch_bounds(256,2) opens the VGPR budget for the
// A-fragments + 4-tile scheduling window (#pragma unroll 4).
__global__ __launch_bounds__(256, 2) void vq_screen_mfma(
    const unsigned short* __restrict__ zh, const unsigned short* __restrict__ zl,
    const unsigned short* __restrict__ efh, const unsigned short* __restrict__ efl,
    const float* __restrict__ hn,
    int* __restrict__ idx_ws, float* __restrict__ ind_out,
    int* __restrict__ nflag, int* __restrict__ flags, int* __restrict__ hist)
{
    __shared__ __align__(16) unsigned short tiles[16][2048];  // 64 KB: 16 tiles x (eh 2KB | el 2KB)
    __shared__ float hns[KK];                                 // 4 KB persistent halfnorms

    const int tid  = threadIdx.x;
    const int lane = tid & 63;
    const int wv   = tid >> 6;          // 0..3
    const int quad = lane >> 4;
    const int col  = lane & 15;
    const int loff = lane * 8;
    const int pbase = blockIdx.x * 256 + wv * 64;   // 64 points per wave

    // A fragments: 4 point-tiles (zh/zl hold -z). 16 bf16x8 = 64 VGPR, persistent.
    bf16x8 Ah0[4], Ah1[4], Al0[4], Al1[4];
#pragma unroll
    for (int pt = 0; pt < 4; ++pt) {
        const bf16x8* ph = (const bf16x8*)(zh + (size_t)(pbase + pt * 16 + col) * DD + quad * 8);
        const bf16x8* pl = (const bf16x8*)(zl + (size_t)(pbase + pt * 16 + col) * DD + quad * 8);
        Ah0[pt] = ph[0]; Ah1[pt] = ph[4];
        Al0[pt] = pl[0]; Al1[pt] = pl[4];
    }

    // persistent halfnorms -> LDS (one float4 per thread)
    ((float4*)hns)[tid] = ((const float4*)hn)[tid];

    float best[4][4], best2[4][4];
    int   bidx[4][4];
#pragma unroll
    for (int pt = 0; pt < 4; ++pt)
#pragma unroll
        for (int r = 0; r < 4; ++r) { best[pt][r] = 1e30f; best2[pt][r] = 1e30f; bidx[pt][r] = 0; }

    // staging source: threads 0..127 stream efh, 128..255 stream efl (16B per instr)
    const unsigned short* sg = (tid < 128 ? efh : efl) + (tid & 127) * 8;

    for (int Q = 0; Q < 4; ++Q) {
        __syncthreads();   // previous quarter fully consumed by all waves

        // stage 64 KB quarter: 16 x global_load_lds(16B) per thread, layout-preserving
#pragma unroll
        for (int k = 0; k < 16; ++k)
            gload_lds16(sg + (size_t)(Q * 16 + k) * 1024, &tiles[k][0] + tid * 8);
        asm volatile("s_waitcnt vmcnt(0)" ::: "memory");
        __syncthreads();

        // sweep 16 resident tiles: no sync, no vm ops (hn from LDS)
#pragma unroll 4
        for (int tt = 0; tt < 16; ++tt) {
            const unsigned short* buf = &tiles[tt][0];
            const bf16x8 Bh0 = *(const bf16x8*)(buf + loff);
            const bf16x8 Bh1 = *(const bf16x8*)(buf + 512 + loff);
            const bf16x8 Bl0 = *(const bf16x8*)(buf + 1024 + loff);
            const bf16x8 Bl1 = *(const bf16x8*)(buf + 1536 + loff);
            const int tg = Q * 16 + tt;
            const float chn = hns[tg * 16 + col];

            // s = 0.5||e||^2 - z·e : 8 independent chains (4x p depth-4, 4x q depth-2)
            f32x4 p[4], q[4];
#pragma unroll
            for (int pt = 0; pt < 4; ++pt) {
                p[pt] = (f32x4){chn, chn, chn, chn};
                q[pt] = (f32x4){0.f, 0.f, 0.f, 0.f};
            }
#pragma unroll
            for (int pt = 0; pt < 4; ++pt)
                p[pt] = __builtin_amdgcn_mfma_f32_16x16x32_bf16(Ah0[pt], Bh0, p[pt], 0, 0, 0);
#pragma unroll
            for (int pt = 0; pt < 4; ++pt)
                q[pt] = __builtin_amdgcn_mfma_f32_16x16x32_bf16(Al0[pt], Bh0, q[pt], 0, 0, 0);
#pragma unroll
            for (int pt = 0; pt < 4; ++pt)
                p[pt] = __builtin_amdgcn_mfma_f32_16x16x32_bf16(Ah1[pt], Bh1, p[pt], 0, 0, 0);
#pragma unroll
            for (int pt = 0; pt < 4; ++pt)
                q[pt] = __builtin_amdgcn_mfma_f32_16x16x32_bf16(Al1[pt], Bh1, q[pt], 0, 0, 0);
#pragma unroll
            for (int pt = 0; pt < 4; ++pt)
                p[pt] = __builtin_amdgcn_mfma_f32_16x16x32_bf16(Ah0[pt], Bl0, p[pt], 0, 0, 0);
#pragma unroll
            for (int pt = 0; pt < 4; ++pt)
                p[pt] = __builtin_amdgcn_mfma_f32_16x16x32_bf16(Ah1[pt], Bl1, p[pt], 0, 0, 0);

            const int code = tg * 16 + col;
#pragma unroll
            for (int pt = 0; pt < 4; ++pt)
#pragma unroll
                for (int r = 0; r < 4; ++r) {
                    const float s = p[pt][r] + q[pt][r];
                    best2[pt][r] = __builtin_amdgcn_fmed3f(best[pt][r], best2[pt][r], s);
                    bidx[pt][r] = (s < best[pt][r]) ? code : bidx[pt][r];
                    best[pt][r] = fminf(best[pt][r], s);
                }
        }
    }

    // merge across the 16 cols of each quad-group (disjoint code sets)
#pragma unroll
    for (int off = 1; off < 16; off <<= 1) {
#pragma unroll
        for (int pt = 0; pt < 4; ++pt)
#pragma unroll
            for (int r = 0; r < 4; ++r) {
                const float ob  = __shfl_xor(best[pt][r],  off, 64);
                const float ob2 = __shfl_xor(best2[pt][r], off, 64);
                const int   oi  = __shfl_xor(bidx[pt][r],  off, 64);
                const float nb2 = fminf(fminf(best2[pt][r], ob2), fmaxf(best[pt][r], ob));
                if (ob < best[pt][r]) { best[pt][r] = ob; bidx[pt][r] = oi; }
                best2[pt][r] = nb2;
            }
    }

    if (col == 0) {
#pragma unroll
        for (int pt = 0; pt < 4; ++pt)
#pragma unroll
            for (int r = 0; r < 4; ++r) {
                const int n0 = pbase + pt * 16 + quad * 4 + r;
                idx_ws[n0] = bidx[pt][r];
                ind_out[n0] = (float)bidx[pt][r];
                atomicAdd(&hist[bidx[pt][r]], 1);
                if (best2[pt][r] - best[pt][r] < MARGIN_TH) {
                    const int pos = atomicAdd(nflag, 1);
                    flags[pos] = n0;
                }
            }
    }
}

// ---------------- K1c: fp64 exact rescan for near-tie points + histogram repair ----------------
__global__ __launch_bounds__(256) void vq_fallback(
    const float* __restrict__ z, const float* __restrict__ emb,
    int* __restrict__ idx_ws, float* __restrict__ ind_out,
    const int* __restrict__ nflag, const int* __restrict__ flags,
    int* __restrict__ hist)
{
    __shared__ float zs[4][DD];
    const int total = *nflag;
    const int lane = threadIdx.x & 63;
    const int wid = threadIdx.x >> 6;
    const int gw = blockIdx.x * 4 + wid;

    for (int i = gw; i < total; i += gridDim.x * 4) {
        const int n = flags[i];
        const int b = n >> 12, t = n & 4095;
        zs[wid][lane] = z[((size_t)b * DD + lane) * TD + t];
        __builtin_amdgcn_s_waitcnt(0);
        double best = 1e300;
        int bi = KK;
        for (int kc = 0; kc < KK / 64; ++kc) {
            const int k = kc * 64 + lane;
            const float4* e = (const float4*)(emb + (size_t)k * DD);
            double dot = 0.0, nn = 0.0;
#pragma unroll
            for (int j = 0; j < 16; ++j) {
                float4 ev = e[j];
                double e0 = (double)ev.x, e1 = (double)ev.y, e2 = (double)ev.z, e3 = (double)ev.w;
                nn = fma(e0, e0, fma(e1, e1, fma(e2, e2, fma(e3, e3, nn))));
                dot = fma((double)zs[wid][4 * j + 0], e0,
                      fma((double)zs[wid][4 * j + 1], e1,
                      fma((double)zs[wid][4 * j + 2], e2,
                      fma((double)zs[wid][4 * j + 3], e3, dot))));
            }
            double s = 0.5 * nn - dot;
            if (s < best || (s == best && k < bi)) { best = s; bi = k; }
        }
        for (int off = 32; off > 0; off >>= 1) {
            double os = __shfl_down(best, off, 64);
            int oi = __shfl_down(bi, off, 64);
            if (os < best || (os == best && oi < bi)) { best = os; bi = oi; }
        }
        if (lane == 0) {
            const int old = idx_ws[n];
            if (bi != old) {
                idx_ws[n] = bi;
                ind_out[n] = (float)bi;
                atomicAdd(&hist[old], -1);
                atomicAdd(&hist[bi], 1);
            }
        }
    }
}

// ---------------- K2b: exclusive scan -> cursor, plus Laplace smoothing -> rsmo ----------------
__global__ __launch_bounds__(1024) void vq_prefix_smo(
    const int* __restrict__ hist, const float* __restrict__ cs,
    int* __restrict__ cursor, float* __restrict__ rsmo)
{
    __shared__ int tmp[KK];
    __shared__ double dred[KK];
    const int k = threadIdx.x;
    const int c = hist[k];
    tmp[k] = c;
    const double ncs = 0.99 * (double)cs[k] + 0.01 * (double)c;
    dred[k] = ncs;
    __syncthreads();
    for (int off = 1; off < KK; off <<= 1) {
        int u = (k >= off) ? tmp[k - off] : 0;
        __syncthreads();
        tmp[k] += u;
        __syncthreads();
    }
    cursor[k] = tmp[k] - c;  // exclusive
    for (int s = 512; s > 0; s >>= 1) {
        if (k < s) dred[k] += dred[k + s];
        __syncthreads();
    }
    const double nsum = dred[0];
    const double smo = (ncs + 1e-5) / (nsum + (double)KK * 1e-5) * nsum;
    rsmo[k] = (float)(1.0 / smo);
}

// ---------------- K2c: scatter point ids into per-code lists ----------------
__global__ __launch_bounds__(256) void vq_scatter(const int* __restrict__ idx_ws,
                                                  int* __restrict__ cursor, int* __restrict__ order)
{
    const int n = blockIdx.x * 256 + threadIdx.x;
    const int bi = idx_ws[n];
    const int pos = atomicAdd(&cursor[bi], 1);
    order[pos] = n;
}

// ---------------- K2d: balanced segment sum (zh/zl hold -z -> negate at flush) ----------------
__global__ __launch_bounds__(256) void vq_esum2(
    const unsigned short* __restrict__ zh, const unsigned short* __restrict__ zl,
    const int* __restrict__ idx_ws, const int* __restrict__ order,
    float* __restrict__ esum)
{
    const int tid = threadIdx.x;
    const int lane = tid & 63;
    const int w = tid >> 6;
    const int base = blockIdx.x * 256 + w * 64;   // this wave's 64 sorted positions

    const int pid_l = order[base + lane];          // coalesced
    const int code_l = idx_ws[pid_l];              // gather (one per lane)

    float v[64];
#pragma unroll
    for (int j = 0; j < 64; ++j) {
        const int pj = __shfl(pid_l, j, 64);
        const size_t o = (size_t)pj * DD + lane;   // 128 B coalesced per row
        v[j] = bf2f(zh[o]) + bf2f(zl[o]);
    }

    float racc = 0.f;
    int cur = __shfl(code_l, 0, 64);
#pragma unroll
    for (int j = 0; j < 64; ++j) {
        const int cj = __shfl(code_l, j, 64);      // wave-uniform
        if (cj != cur) {
            atomicAdd(&esum[(size_t)cur * DD + lane], -racc);
            racc = 0.f;
            cur = cj;
        }
        racc += v[j];
    }
    atomicAdd(&esum[(size_t)cur * DD + lane], -racc);
}

// ---------------- K3: new embedding (parallel) ----------------
__global__ __launch_bounds__(256) void vq_newE(
    const float* __restrict__ avg, const float* __restrict__ esum,
    const float* __restrict__ rsmo, float* __restrict__ newE)
{
    const int j = blockIdx.x * 256 + threadIdx.x;   // 65536 total
    newE[j] = (float)((0.99 * (double)avg[j] + 0.01 * (double)esum[j]) * (double)rsmo[j >> 6]);
}

// ---------------- K4: gather z_q + commitment loss (finalize fused) ----------------
__global__ __launch_bounds__(256) void vq_gather_loss(
    const float* __restrict__ z, const float* __restrict__ newE,
    const int* __restrict__ idx_ws, float* __restrict__ zq_out,
    double* __restrict__ loss_acc, int* __restrict__ done_cnt,
    float* __restrict__ loss_out)
{
    const int tid = threadIdx.x;
    const int n = blockIdx.x * 256 + tid;
    const int b = n >> 12;
    const int t = n & 4095;
    const float* zb = z + ((size_t)b * DD) * TD + t;
    float* ob = zq_out + ((size_t)b * DD) * TD + t;
    const int bi = idx_ws[n];
    const float* e = newE + (size_t)bi * DD;
    double acc = 0.0;
#pragma unroll
    for (int d = 0; d < DD; ++d) {
        float q = e[d];
        float zv = zb[(size_t)d * TD];
        ob[(size_t)d * TD] = q;
        float df = zv - q;
        acc = fma((double)df, (double)df, acc);
    }
    for (int off = 32; off > 0; off >>= 1) acc += __shfl_down(acc, off, 64);
    __shared__ double wsum[4];
    const int wid = tid >> 6, lane = tid & 63;
    if (lane == 0) wsum[wid] = acc;
    __syncthreads();
    if (tid == 0) {
        atomicAdd(loss_acc, wsum[0] + wsum[1] + wsum[2] + wsum[3]);
        __threadfence();
        const int prev = atomicAdd(done_cnt, 1);
        if (prev == gridDim.x - 1) {
            __threadfence();
            *loss_out = (float)(0.25 * (*loss_acc) / (double)(N_PTS * DD));
        }
    }
}

extern "C" void kernel_launch(void* const* d_in, const int* in_sizes, int n_in,
                              void* d_out, int out_size, void* d_ws, size_t ws_size,
                              hipStream_t stream) {
    const float* z    = (const float*)d_in[0];   // [32, 64, 4096]
    const float* emb  = (const float*)d_in[1];   // [1024, 64]
    const float* cs   = (const float*)d_in[2];   // [1024]
    const float* avg  = (const float*)d_in[3];   // [1024, 64]

    float* out      = (float*)d_out;
    float* zq_out   = out;                // 8388608 floats (32 MiB)
    float* loss_out = out + 8388608;      // 1
    float* ind_out  = out + 8388609;      // 131072 (indices as float)

    // z_hi/z_lo bf16 [N][D] exactly fill the z_q region (dead before K4 rewrites it)
    unsigned short* zh = (unsigned short*)d_out;                       // 16 MiB
    unsigned short* zl = (unsigned short*)((char*)d_out + 16777216);   // 16 MiB

    char* ws = (char*)d_ws;
    int*            idx_ws   = (int*)ws;                     // 512 KB @ 0
    float*          newE     = (float*)(ws + 524288);        // 256 KB
    float*          esum     = (float*)(ws + 786432);        // 256 KB [memset]
    int*            hist     = (int*)(ws + 1048576);         // 4 KB   [memset]
    int*            nflag    = (int*)(ws + 1052672);         // 4 B    [memset]
    int*            done_cnt = (int*)(ws + 1052676);         // 4 B    [memset]
    double*         loss_acc = (double*)(ws + 1052680);      // 8 B    [memset]
    float*          halfnorm = (float*)(ws + 1052688);       // 4 KB
    int*            cursor   = (int*)(ws + 1056784);         // 4 KB
    int*            flags    = (int*)(ws + 1060880);         // 512 KB
    int*            order    = (int*)(ws + 1585168);         // 512 KB
    unsigned short* efh      = (unsigned short*)(ws + 2109456); // 128 KB (fragment-ordered hi)
    unsigned short* efl      = (unsigned short*)(ws + 2240528); // 128 KB (fragment-ordered lo)
    float*          rsmo     = (float*)(ws + 2371600);       // 4 KB (end ~2.38 MB)

    // zero esum + hist + nflag + done_cnt + loss_acc (contiguous 786432..1052688)
    hipMemsetAsync(ws + 786432, 0, 266256, stream);

    vq_prep<<<2048, 256, 0, stream>>>(z, zh, zl);
    vq_eprep<<<4, 256, 0, stream>>>(emb, efh, efl, halfnorm);
    vq_screen_mfma<<<512, 256, 0, stream>>>(zh, zl, efh, efl, halfnorm,
                                            idx_ws, ind_out, nflag, flags, hist);
    vq_fallback<<<128, 256, 0, stream>>>(z, emb, idx_ws, ind_out, nflag, flags, hist);
    vq_prefix_smo<<<1, 1024, 0, stream>>>(hist, cs, cursor, rsmo);
    vq_scatter<<<N_PTS / 256, 256, 0, stream>>>(idx_ws, cursor, order);
    vq_esum2<<<N_PTS / 256, 256, 0, stream>>>(zh, zl, idx_ws, order, esum);
    vq_newE<<<256, 256, 0, stream>>>(avg, esum, rsmo, newE);
    vq_gather_loss<<<N_PTS / 256, 256, 0, stream>>>(z, newE, idx_ws, zq_out,
                                                    loss_acc, done_cnt, loss_out);
}

// Round 7
// 294.401 us; speedup vs baseline: 1.1539x; 1.1539x over previous
//
#include <hip/hip_runtime.h>

#define N_PTS 131072
#define TD 4096
#define DD 64
#define KK 1024
#define MARGIN_TH 2e-3f

typedef short bf16x8 __attribute__((ext_vector_type(8)));
typedef float f32x4  __attribute__((ext_vector_type(4)));

__device__ inline unsigned short f2bf(float f) {           // RNE float->bf16
    unsigned u = __float_as_uint(f);
    unsigned r = u + 0x7FFFu + ((u >> 16) & 1u);
    return (unsigned short)(r >> 16);
}
__device__ inline float bf2f(unsigned short h) {
    return __uint_as_float(((unsigned)h) << 16);
}

// ---------------- K0a: transpose z[B,D,T] -> NEGATED z_hi/z_lo bf16 [N,D] ----------------
// Storing -z lets the screen fold 0.5*||e||^2 into the MFMA accumulator (s = hn + (-z)·e).
__global__ __launch_bounds__(256) void vq_prep(const float* __restrict__ z,
                                               unsigned short* __restrict__ zh,
                                               unsigned short* __restrict__ zl)
{
    __shared__ float tile[64][65];
    const int tid = threadIdx.x;
    const int b = blockIdx.x >> 6;
    const int t0 = (blockIdx.x & 63) * 64;

    const int d = tid >> 2, tq = tid & 3;
#pragma unroll
    for (int it = 0; it < 4; ++it) {
        const int tt = tq * 16 + it * 4;
        const float4 v = *(const float4*)(z + ((size_t)b * DD + d) * TD + t0 + tt);
        tile[d][tt] = v.x; tile[d][tt + 1] = v.y; tile[d][tt + 2] = v.z; tile[d][tt + 3] = v.w;
    }
    __syncthreads();

    const int p = tid >> 2, dg = tid & 3;
    bf16x8 h0, h1, l0, l1;
#pragma unroll
    for (int j = 0; j < 8; ++j) {
        const float v0 = -tile[dg * 16 + j][p];
        const unsigned short a = f2bf(v0);
        h0[j] = (short)a; l0[j] = (short)f2bf(v0 - bf2f(a));
        const float v1 = -tile[dg * 16 + 8 + j][p];
        const unsigned short c = f2bf(v1);
        h1[j] = (short)c; l1[j] = (short)f2bf(v1 - bf2f(c));
    }
    const size_t o = ((size_t)(b * TD + t0 + p)) * DD + dg * 16;
    *(bf16x8*)(zh + o) = h0;
    *(bf16x8*)(zh + o + 8) = h1;
    *(bf16x8*)(zl + o) = l0;
    *(bf16x8*)(zl + o + 8) = l1;
}

// ---------------- K0b: emb -> MFMA-fragment-ordered e_hi/e_lo + fp64-exact half norms ----
// TIGHT layout, 1024 ushorts per 16-code tile (exactly 128 KB per array):
//   code k = t*16+col, dim d = q*8+j (q=0..7, half=q>>2):
//   ef[t*1024 + half*512 + ((q&3)*16 + col)*8 + j]
__global__ __launch_bounds__(256) void vq_eprep(const float* __restrict__ emb,
                                                unsigned short* __restrict__ efh,
                                                unsigned short* __restrict__ efl,
                                                float* __restrict__ halfnorm)
{
    const int k = blockIdx.x * 256 + threadIdx.x;
    if (k >= KK) return;
    const int t = k >> 4, col = k & 15;
    const float* e = emb + (size_t)k * DD;
    double s = 0.0;
#pragma unroll
    for (int d = 0; d < DD; ++d) {
        const float v = e[d];
        const double dv = (double)v;
        s = fma(dv, dv, s);
        const unsigned short h = f2bf(v);
        const int q = d >> 3, j = d & 7;
        const size_t pos = (size_t)t * 1024 + (q >> 2) * 512 + ((q & 3) * 16 + col) * 8 + j;
        efh[pos] = h;
        efl[pos] = f2bf(v - bf2f(h));
    }
    halfnorm[k] = (float)(0.5 * s);
}

// ---------------- K1: MFMA screen v7 — high-occupancy (16 pts/wave, 6 blocks/CU) ----------
// Diagnosis across r0-r6: latency-bound screen, never above 2.5 blocks/CU. v7 shrinks
// per-wave state to ONE point-tile (A = 16 VGPR, one 6-deep MFMA chain, 4-reg bookkeep)
// and launches 2048 blocks of 256 threads with an 8 KB double-buffered tile (r0's proven
// reg-staged LDS scheme, 1 barrier/tile). launch_bounds(256,6) -> ~6 blocks/CU resident:
// barrier waits and ds/MFMA latencies hide behind 5 other blocks. Fused-hist atomics
// REMOVED (restored as the separate LDS-privatized vq_hist kernel, r0 order).
__global__ __launch_bounds__(256, 6) void vq_screen_mfma(
    const unsigned short* __restrict__ zh, const unsigned short* __restrict__ zl,
    const unsigned short* __restrict__ efh, const unsigned short* __restrict__ efl,
    const float* __restrict__ hn,
    int* __restrict__ idx_ws, float* __restrict__ ind_out,
    int* __restrict__ nflag, int* __restrict__ flags)
{
    __shared__ __align__(16) unsigned short tiles[2][2048];  // 8 KB: double-buffered 16-code tile

    const int tid  = threadIdx.x;
    const int lane = tid & 63;
    const int wv   = tid >> 6;          // 0..3
    const int quad = lane >> 4;
    const int col  = lane & 15;
    const int loff = lane * 8;
    const int pbase = blockIdx.x * 64 + wv * 16;   // 16 points per wave

    // A fragments: one point-tile (zh/zl hold -z)
    const bf16x8* ph = (const bf16x8*)(zh + (size_t)(pbase + col) * DD + quad * 8);
    const bf16x8* pl = (const bf16x8*)(zl + (size_t)(pbase + col) * DD + quad * 8);
    const bf16x8 Ah0 = ph[0], Ah1 = ph[4];
    const bf16x8 Al0 = pl[0], Al1 = pl[4];

    // staging: thread tid owns 16B chunk tid of each 4 KB tile (eh 2KB | el 2KB), linear
    const unsigned short* sg = (tid < 128) ? (efh + tid * 8) : (efl + (tid - 128) * 8);

    // preload tile 0 (reg-staged; VALU staging doubles as latency filler)
    *(bf16x8*)(&tiles[0][tid * 8]) = *(const bf16x8*)(sg);
    float chn = hn[col];

    float best[4]  = {1e30f, 1e30f, 1e30f, 1e30f};
    float best2[4] = {1e30f, 1e30f, 1e30f, 1e30f};
    int   bidx[4]  = {0, 0, 0, 0};

    __syncthreads();

    for (int t = 0; t < KK / 16; ++t) {
        const int cur = t & 1;

        // issue next tile's global loads early (no wait yet)
        bf16x8 nr;
        float nhn = 0.f;
        if (t < 63) {
            nr = *(const bf16x8*)(sg + (size_t)(t + 1) * 1024);
            nhn = hn[(t + 1) * 16 + col];
        }

        // B fragments from current LDS buffer (linear, conflict-free)
        const unsigned short* buf = &tiles[cur][0];
        const bf16x8 Bh0 = *(const bf16x8*)(buf + loff);
        const bf16x8 Bh1 = *(const bf16x8*)(buf + 512 + loff);
        const bf16x8 Bl0 = *(const bf16x8*)(buf + 1024 + loff);
        const bf16x8 Bl1 = *(const bf16x8*)(buf + 1536 + loff);

        // write next tile into the other buffer (safe: all reads of it ended at t-1's barrier)
        if (t < 63) *(bf16x8*)(&tiles[cur ^ 1][tid * 8]) = nr;

        // s = 0.5||e||^2 - z·e accumulated in one 6-deep MFMA chain
        f32x4 p = {chn, chn, chn, chn};
        p = __builtin_amdgcn_mfma_f32_16x16x32_bf16(Ah0, Bh0, p, 0, 0, 0);
        p = __builtin_amdgcn_mfma_f32_16x16x32_bf16(Ah1, Bh1, p, 0, 0, 0);
        p = __builtin_amdgcn_mfma_f32_16x16x32_bf16(Al0, Bh0, p, 0, 0, 0);
        p = __builtin_amdgcn_mfma_f32_16x16x32_bf16(Al1, Bh1, p, 0, 0, 0);
        p = __builtin_amdgcn_mfma_f32_16x16x32_bf16(Ah0, Bl0, p, 0, 0, 0);
        p = __builtin_amdgcn_mfma_f32_16x16x32_bf16(Ah1, Bl1, p, 0, 0, 0);

        const int code = t * 16 + col;
#pragma unroll
        for (int r = 0; r < 4; ++r) {
            const float s = p[r];
            best2[r] = __builtin_amdgcn_fmed3f(best[r], best2[r], s);   // new 2nd-best
            bidx[r] = (s < best[r]) ? code : bidx[r];
            best[r] = fminf(best[r], s);
        }

        __syncthreads();
        chn = nhn;
    }

    // merge across the 16 cols of each quad-group (disjoint code sets)
#pragma unroll
    for (int off = 1; off < 16; off <<= 1) {
#pragma unroll
        for (int r = 0; r < 4; ++r) {
            const float ob  = __shfl_xor(best[r],  off, 64);
            const float ob2 = __shfl_xor(best2[r], off, 64);
            const int   oi  = __shfl_xor(bidx[r],  off, 64);
            const float nb2 = fminf(fminf(best2[r], ob2), fmaxf(best[r], ob));
            if (ob < best[r]) { best[r] = ob; bidx[r] = oi; }
            best2[r] = nb2;
        }
    }

    if (col == 0) {
#pragma unroll
        for (int r = 0; r < 4; ++r) {
            const int n0 = pbase + quad * 4 + r;
            idx_ws[n0] = bidx[r];
            ind_out[n0] = (float)bidx[r];
            if (best2[r] - best[r] < MARGIN_TH) {
                const int pos = atomicAdd(nflag, 1);
                flags[pos] = n0;
            }
        }
    }
}

// ---------------- K1c: fp64 exact rescan for near-tie points (wave per point) ----------------
__global__ __launch_bounds__(256) void vq_fallback(
    const float* __restrict__ z, const float* __restrict__ emb,
    int* __restrict__ idx_ws, float* __restrict__ ind_out,
    const int* __restrict__ nflag, const int* __restrict__ flags)
{
    __shared__ float zs[4][DD];
    const int total = *nflag;
    const int lane = threadIdx.x & 63;
    const int wid = threadIdx.x >> 6;
    const int gw = blockIdx.x * 4 + wid;

    for (int i = gw; i < total; i += gridDim.x * 4) {
        const int n = flags[i];
        const int b = n >> 12, t = n & 4095;
        zs[wid][lane] = z[((size_t)b * DD + lane) * TD + t];
        __builtin_amdgcn_s_waitcnt(0);
        double best = 1e300;
        int bi = KK;
        for (int kc = 0; kc < KK / 64; ++kc) {
            const int k = kc * 64 + lane;
            const float4* e = (const float4*)(emb + (size_t)k * DD);
            double dot = 0.0, nn = 0.0;
#pragma unroll
            for (int j = 0; j < 16; ++j) {
                float4 ev = e[j];
                double e0 = (double)ev.x, e1 = (double)ev.y, e2 = (double)ev.z, e3 = (double)ev.w;
                nn = fma(e0, e0, fma(e1, e1, fma(e2, e2, fma(e3, e3, nn))));
                dot = fma((double)zs[wid][4 * j + 0], e0,
                      fma((double)zs[wid][4 * j + 1], e1,
                      fma((double)zs[wid][4 * j + 2], e2,
                      fma((double)zs[wid][4 * j + 3], e3, dot))));
            }
            double s = 0.5 * nn - dot;
            if (s < best || (s == best && k < bi)) { best = s; bi = k; }
        }
        for (int off = 32; off > 0; off >>= 1) {
            double os = __shfl_down(best, off, 64);
            int oi = __shfl_down(bi, off, 64);
            if (os < best || (os == best && oi < bi)) { best = os; bi = oi; }
        }
        if (lane == 0) { idx_ws[n] = bi; ind_out[n] = (float)bi; }
    }
}

// ---------------- K2a: histogram of final indices (LDS-privatized) ----------------
__global__ __launch_bounds__(256) void vq_hist(const int* __restrict__ idx_ws, int* __restrict__ hist)
{
    __shared__ int h[KK];
    for (int i = threadIdx.x; i < KK; i += 256) h[i] = 0;
    __syncthreads();
    const int base = blockIdx.x * 2048;
#pragma unroll
    for (int j = 0; j < 8; ++j)
        atomicAdd(&h[idx_ws[base + j * 256 + threadIdx.x]], 1);
    __syncthreads();
    for (int i = threadIdx.x; i < KK; i += 256)
        if (h[i]) atomicAdd(&hist[i], h[i]);
}

// ---------------- K2b: exclusive scan -> cursor, plus Laplace smoothing -> rsmo ----------------
__global__ __launch_bounds__(1024) void vq_prefix_smo(
    const int* __restrict__ hist, const float* __restrict__ cs,
    int* __restrict__ cursor, float* __restrict__ rsmo)
{
    __shared__ int tmp[KK];
    __shared__ double dred[KK];
    const int k = threadIdx.x;
    const int c = hist[k];
    tmp[k] = c;
    const double ncs = 0.99 * (double)cs[k] + 0.01 * (double)c;
    dred[k] = ncs;
    __syncthreads();
    for (int off = 1; off < KK; off <<= 1) {
        int u = (k >= off) ? tmp[k - off] : 0;
        __syncthreads();
        tmp[k] += u;
        __syncthreads();
    }
    cursor[k] = tmp[k] - c;  // exclusive
    for (int s = 512; s > 0; s >>= 1) {
        if (k < s) dred[k] += dred[k + s];
        __syncthreads();
    }
    const double nsum = dred[0];
    const double smo = (ncs + 1e-5) / (nsum + (double)KK * 1e-5) * nsum;
    rsmo[k] = (float)(1.0 / smo);
}

// ---------------- K2c: scatter point ids into per-code lists ----------------
__global__ __launch_bounds__(256) void vq_scatter(const int* __restrict__ idx_ws,
                                                  int* __restrict__ cursor, int* __restrict__ order)
{
    const int n = blockIdx.x * 256 + threadIdx.x;
    const int bi = idx_ws[n];
    const int pos = atomicAdd(&cursor[bi], 1);
    order[pos] = n;
}

// ---------------- K2d: balanced segment sum (zh/zl hold -z -> negate at flush) ----------------
__global__ __launch_bounds__(256) void vq_esum2(
    const unsigned short* __restrict__ zh, const unsigned short* __restrict__ zl,
    const int* __restrict__ idx_ws, const int* __restrict__ order,
    float* __restrict__ esum)
{
    const int tid = threadIdx.x;
    const int lane = tid & 63;
    const int w = tid >> 6;
    const int base = blockIdx.x * 256 + w * 64;   // this wave's 64 sorted positions

    const int pid_l = order[base + lane];          // coalesced
    const int code_l = idx_ws[pid_l];              // gather (one per lane)

    float v[64];
#pragma unroll
    for (int j = 0; j < 64; ++j) {
        const int pj = __shfl(pid_l, j, 64);
        const size_t o = (size_t)pj * DD + lane;   // 128 B coalesced per row
        v[j] = bf2f(zh[o]) + bf2f(zl[o]);
    }

    float racc = 0.f;
    int cur = __shfl(code_l, 0, 64);
#pragma unroll
    for (int j = 0; j < 64; ++j) {
        const int cj = __shfl(code_l, j, 64);      // wave-uniform
        if (cj != cur) {
            atomicAdd(&esum[(size_t)cur * DD + lane], -racc);
            racc = 0.f;
            cur = cj;
        }
        racc += v[j];
    }
    atomicAdd(&esum[(size_t)cur * DD + lane], -racc);
}

// ---------------- K3: new embedding (parallel) ----------------
__global__ __launch_bounds__(256) void vq_newE(
    const float* __restrict__ avg, const float* __restrict__ esum,
    const float* __restrict__ rsmo, float* __restrict__ newE)
{
    const int j = blockIdx.x * 256 + threadIdx.x;   // 65536 total
    newE[j] = (float)((0.99 * (double)avg[j] + 0.01 * (double)esum[j]) * (double)rsmo[j >> 6]);
}

// ---------------- K4: gather z_q + commitment loss (finalize fused) ----------------
__global__ __launch_bounds__(256) void vq_gather_loss(
    const float* __restrict__ z, const float* __restrict__ newE,
    const int* __restrict__ idx_ws, float* __restrict__ zq_out,
    double* __restrict__ loss_acc, int* __restrict__ done_cnt,
    float* __restrict__ loss_out)
{
    const int tid = threadIdx.x;
    const int n = blockIdx.x * 256 + tid;
    const int b = n >> 12;
    const int t = n & 4095;
    const float* zb = z + ((size_t)b * DD) * TD + t;
    float* ob = zq_out + ((size_t)b * DD) * TD + t;
    const int bi = idx_ws[n];
    const float* e = newE + (size_t)bi * DD;
    double acc = 0.0;
#pragma unroll
    for (int d = 0; d < DD; ++d) {
        float q = e[d];
        float zv = zb[(size_t)d * TD];
        ob[(size_t)d * TD] = q;
        float df = zv - q;
        acc = fma((double)df, (double)df, acc);
    }
    for (int off = 32; off > 0; off >>= 1) acc += __shfl_down(acc, off, 64);
    __shared__ double wsum[4];
    const int wid = tid >> 6, lane = tid & 63;
    if (lane == 0) wsum[wid] = acc;
    __syncthreads();
    if (tid == 0) {
        atomicAdd(loss_acc, wsum[0] + wsum[1] + wsum[2] + wsum[3]);
        __threadfence();
        const int prev = atomicAdd(done_cnt, 1);
        if (prev == gridDim.x - 1) {
            __threadfence();
            *loss_out = (float)(0.25 * (*loss_acc) / (double)(N_PTS * DD));
        }
    }
}

extern "C" void kernel_launch(void* const* d_in, const int* in_sizes, int n_in,
                              void* d_out, int out_size, void* d_ws, size_t ws_size,
                              hipStream_t stream) {
    const float* z    = (const float*)d_in[0];   // [32, 64, 4096]
    const float* emb  = (const float*)d_in[1];   // [1024, 64]
    const float* cs   = (const float*)d_in[2];   // [1024]
    const float* avg  = (const float*)d_in[3];   // [1024, 64]

    float* out      = (float*)d_out;
    float* zq_out   = out;                // 8388608 floats (32 MiB)
    float* loss_out = out + 8388608;      // 1
    float* ind_out  = out + 8388609;      // 131072 (indices as float)

    // z_hi/z_lo bf16 [N][D] exactly fill the z_q region (dead before K4 rewrites it)
    unsigned short* zh = (unsigned short*)d_out;                       // 16 MiB
    unsigned short* zl = (unsigned short*)((char*)d_out + 16777216);   // 16 MiB

    char* ws = (char*)d_ws;
    int*            idx_ws   = (int*)ws;                     // 512 KB @ 0
    float*          newE     = (float*)(ws + 524288);        // 256 KB
    float*          esum     = (float*)(ws + 786432);        // 256 KB [memset]
    int*            hist     = (int*)(ws + 1048576);         // 4 KB   [memset]
    int*            nflag    = (int*)(ws + 1052672);         // 4 B    [memset]
    int*            done_cnt = (int*)(ws + 1052676);         // 4 B    [memset]
    double*         loss_acc = (double*)(ws + 1052680);      // 8 B    [memset]
    float*          halfnorm = (float*)(ws + 1052688);       // 4 KB
    int*            cursor   = (int*)(ws + 1056784);         // 4 KB
    int*            flags    = (int*)(ws + 1060880);         // 512 KB
    int*            order    = (int*)(ws + 1585168);         // 512 KB
    unsigned short* efh      = (unsigned short*)(ws + 2109456); // 128 KB (fragment-ordered hi)
    unsigned short* efl      = (unsigned short*)(ws + 2240528); // 128 KB (fragment-ordered lo)
    float*          rsmo     = (float*)(ws + 2371600);       // 4 KB (end ~2.38 MB)

    // zero esum + hist + nflag + done_cnt + loss_acc (contiguous 786432..1052688)
    hipMemsetAsync(ws + 786432, 0, 266256, stream);

    vq_prep<<<2048, 256, 0, stream>>>(z, zh, zl);
    vq_eprep<<<4, 256, 0, stream>>>(emb, efh, efl, halfnorm);
    vq_screen_mfma<<<N_PTS / 64, 256, 0, stream>>>(zh, zl, efh, efl, halfnorm,
                                                   idx_ws, ind_out, nflag, flags);
    vq_fallback<<<128, 256, 0, stream>>>(z, emb, idx_ws, ind_out, nflag, flags);
    vq_hist<<<64, 256, 0, stream>>>(idx_ws, hist);
    vq_prefix_smo<<<1, 1024, 0, stream>>>(hist, cs, cursor, rsmo);
    vq_scatter<<<N_PTS / 256, 256, 0, stream>>>(idx_ws, cursor, order);
    vq_esum2<<<N_PTS / 256, 256, 0, stream>>>(zh, zl, idx_ws, order, esum);
    vq_newE<<<256, 256, 0, stream>>>(avg, esum, rsmo, newE);
    vq_gather_loss<<<N_PTS / 256, 256, 0, stream>>>(z, newE, idx_ws, zq_out,
                                                    loss_acc, done_cnt, loss_out);
}

// Round 8
// 286.960 us; speedup vs baseline: 1.1838x; 1.0259x over previous
//
#include <hip/hip_runtime.h>

#define N_PTS 131072
#define TD 4096
#define DD 64
#define KK 1024
#define MARGIN_TH 2e-3f

typedef short bf16x8 __attribute__((ext_vector_type(8)));
typedef float f32x4  __attribute__((ext_vector_type(4)));

__device__ inline unsigned short f2bf(float f) {           // RNE float->bf16
    unsigned u = __float_as_uint(f);
    unsigned r = u + 0x7FFFu + ((u >> 16) & 1u);
    return (unsigned short)(r >> 16);
}
__device__ inline float bf2f(unsigned short h) {
    return __uint_as_float(((unsigned)h) << 16);
}

__device__ inline void gload_lds16(const unsigned short* g, unsigned short* l) {
    __builtin_amdgcn_global_load_lds(
        (const __attribute__((address_space(1))) unsigned int*)g,
        (__attribute__((address_space(3))) unsigned int*)l, 16, 0, 0);
}

// ---------------- K0: fused prep ----------------
// blocks 0..2047: transpose z[B,D,T] -> NEGATED z_hi/z_lo bf16 [N,D]
//   (storing -z lets the screen fold 0.5*||e||^2 into the MFMA accumulator)
// blocks 2048..2051: emb -> MFMA-fragment-ordered e_hi/e_lo + fp64-exact half norms
//   TIGHT layout, 1024 ushorts per 16-code tile (exactly 128 KB per array):
//   code k = t*16+col, dim d = q*8+j (q=0..7, half=q>>2):
//   ef[t*1024 + half*512 + ((q&3)*16 + col)*8 + j]
__global__ __launch_bounds__(256) void vq_prep(const float* __restrict__ z,
                                               unsigned short* __restrict__ zh,
                                               unsigned short* __restrict__ zl,
                                               const float* __restrict__ emb,
                                               unsigned short* __restrict__ efh,
                                               unsigned short* __restrict__ efl,
                                               float* __restrict__ halfnorm)
{
    __shared__ float tile[64][65];
    const int tid = threadIdx.x;

    if (blockIdx.x >= 2048) {                    // ---- eprep role (4 blocks) ----
        const int k = (blockIdx.x - 2048) * 256 + tid;   // 0..1023
        const int t = k >> 4, col = k & 15;
        const float* e = emb + (size_t)k * DD;
        double s = 0.0;
#pragma unroll
        for (int d = 0; d < DD; ++d) {
            const float v = e[d];
            const double dv = (double)v;
            s = fma(dv, dv, s);
            const unsigned short h = f2bf(v);
            const int q = d >> 3, j = d & 7;
            const size_t pos = (size_t)t * 1024 + (q >> 2) * 512 + ((q & 3) * 16 + col) * 8 + j;
            efh[pos] = h;
            efl[pos] = f2bf(v - bf2f(h));
        }
        halfnorm[k] = (float)(0.5 * s);
        return;
    }

    // ---- transpose role ----
    const int b = blockIdx.x >> 6;
    const int t0 = (blockIdx.x & 63) * 64;

    const int d = tid >> 2, tq = tid & 3;
#pragma unroll
    for (int it = 0; it < 4; ++it) {
        const int tt = tq * 16 + it * 4;
        const float4 v = *(const float4*)(z + ((size_t)b * DD + d) * TD + t0 + tt);
        tile[d][tt] = v.x; tile[d][tt + 1] = v.y; tile[d][tt + 2] = v.z; tile[d][tt + 3] = v.w;
    }
    __syncthreads();

    const int p = tid >> 2, dg = tid & 3;
    bf16x8 h0, h1, l0, l1;
#pragma unroll
    for (int j = 0; j < 8; ++j) {
        const float v0 = -tile[dg * 16 + j][p];
        const unsigned short a = f2bf(v0);
        h0[j] = (short)a; l0[j] = (short)f2bf(v0 - bf2f(a));
        const float v1 = -tile[dg * 16 + 8 + j][p];
        const unsigned short c = f2bf(v1);
        h1[j] = (short)c; l1[j] = (short)f2bf(v1 - bf2f(c));
    }
    const size_t o = ((size_t)(b * TD + t0 + p)) * DD + dg * 16;
    *(bf16x8*)(zh + o) = h0;
    *(bf16x8*)(zh + o + 8) = h1;
    *(bf16x8*)(zl + o) = l0;
    *(bf16x8*)(zl + o + 8) = l1;
}

// ---------------- K1: MFMA screen v8 — r7's TLP x r4's counted-vmcnt DMA staging --------
// 16 pts/wave, 2048 blocks, 6 blocks/CU (r7's proven high-TLP config) PLUS: per-tile
// staging is ONE global_load_lds(16B)/thread into a 4-buffer ring; s_waitcnt vmcnt(2) +
// raw s_barrier per tile (prefetch depth 2 stays in flight across barriers — no vmcnt(0)
// drain, the r0/r7 structural stall). hn lives in persistent LDS so vmcnt counts only
// tile DMAs. No reg-staging VALU. LDS 20 KB x 6 blocks = 120 KB.
__global__ __launch_bounds__(256, 6) void vq_screen_mfma(
    const unsigned short* __restrict__ zh, const unsigned short* __restrict__ zl,
    const unsigned short* __restrict__ efh, const unsigned short* __restrict__ efl,
    const float* __restrict__ hn,
    int* __restrict__ idx_ws, float* __restrict__ ind_out,
    int* __restrict__ nflag, int* __restrict__ flags)
{
    __shared__ __align__(16) unsigned short tiles[4][2048];  // 16 KB ring (4 KB/tile: eh|el)
    __shared__ float hns[KK];                                // 4 KB persistent halfnorms

    const int tid  = threadIdx.x;
    const int lane = tid & 63;
    const int wv   = tid >> 6;          // 0..3
    const int quad = lane >> 4;
    const int col  = lane & 15;
    const int loff = lane * 8;
    const int pbase = blockIdx.x * 64 + wv * 16;   // 16 points per wave

    // A fragments: one point-tile (zh/zl hold -z)
    const bf16x8* ph = (const bf16x8*)(zh + (size_t)(pbase + col) * DD + quad * 8);
    const bf16x8* pl = (const bf16x8*)(zl + (size_t)(pbase + col) * DD + quad * 8);
    const bf16x8 Ah0 = ph[0], Ah1 = ph[4];
    const bf16x8 Al0 = pl[0], Al1 = pl[4];

    // persistent halfnorms -> LDS (one float4 per thread)
    ((float4*)hns)[tid] = ((const float4*)hn)[tid];

    // staging source: thread tid owns 16B chunk tid of each 4 KB tile (eh 2KB | el 2KB)
    const unsigned short* sg = (tid < 128) ? (efh + tid * 8) : (efl + (tid - 128) * 8);

    // pin: all prologue vm ops complete BEFORE any tile DMA -> in-loop vmcnt counts DMAs only
    asm volatile("s_waitcnt vmcnt(0)" ::: "memory");
    __builtin_amdgcn_sched_barrier(0);
    __syncthreads();

#define STAGE(T) gload_lds16(sg + (size_t)(T) * 1024, &tiles[(T) & 3][tid * 8])

    STAGE(0);
    STAGE(1);

    float best[4]  = {1e30f, 1e30f, 1e30f, 1e30f};
    float best2[4] = {1e30f, 1e30f, 1e30f, 1e30f};
    int   bidx[4]  = {0, 0, 0, 0};

#define BODY(T)                                                                     \
    {                                                                               \
        const unsigned short* buf = &tiles[(T) & 3][0];                             \
        const bf16x8 Bh0 = *(const bf16x8*)(buf + loff);                            \
        const bf16x8 Bh1 = *(const bf16x8*)(buf + 512 + loff);                      \
        const bf16x8 Bl0 = *(const bf16x8*)(buf + 1024 + loff);                     \
        const bf16x8 Bl1 = *(const bf16x8*)(buf + 1536 + loff);                     \
        const float chn = hns[(T) * 16 + col];                                      \
        f32x4 p = {chn, chn, chn, chn};                                             \
        p = __builtin_amdgcn_mfma_f32_16x16x32_bf16(Ah0, Bh0, p, 0, 0, 0);          \
        p = __builtin_amdgcn_mfma_f32_16x16x32_bf16(Ah1, Bh1, p, 0, 0, 0);          \
        p = __builtin_amdgcn_mfma_f32_16x16x32_bf16(Al0, Bh0, p, 0, 0, 0);          \
        p = __builtin_amdgcn_mfma_f32_16x16x32_bf16(Al1, Bh1, p, 0, 0, 0);          \
        p = __builtin_amdgcn_mfma_f32_16x16x32_bf16(Ah0, Bl0, p, 0, 0, 0);          \
        p = __builtin_amdgcn_mfma_f32_16x16x32_bf16(Ah1, Bl1, p, 0, 0, 0);          \
        const int code = (T) * 16 + col;                                            \
        _Pragma("unroll")                                                           \
        for (int r = 0; r < 4; ++r) {                                               \
            const float s = p[r];                                                   \
            best2[r] = __builtin_amdgcn_fmed3f(best[r], best2[r], s);               \
            bidx[r] = (s < best[r]) ? code : bidx[r];                               \
            best[r] = fminf(best[r], s);                                            \
        }                                                                           \
    }

    for (int t = 0; t < 62; ++t) {
        STAGE(t + 2);                                      // depth-2 prefetch, stays in flight
        asm volatile("s_waitcnt vmcnt(2)" ::: "memory");   // tile t landed; t+1,t+2 in flight
        __builtin_amdgcn_sched_barrier(0);
        __builtin_amdgcn_s_barrier();                      // raw barrier: no vmcnt(0) drain
        __builtin_amdgcn_sched_barrier(0);
        BODY(t);
    }
    // peeled tail: counts shrink as issues stop
    asm volatile("s_waitcnt vmcnt(1)" ::: "memory");
    __builtin_amdgcn_sched_barrier(0);
    __builtin_amdgcn_s_barrier();
    __builtin_amdgcn_sched_barrier(0);
    BODY(62);
    asm volatile("s_waitcnt vmcnt(0)" ::: "memory");
    __builtin_amdgcn_sched_barrier(0);
    __builtin_amdgcn_s_barrier();
    __builtin_amdgcn_sched_barrier(0);
    BODY(63);

#undef STAGE
#undef BODY

    // merge across the 16 cols of each quad-group (disjoint code sets)
#pragma unroll
    for (int off = 1; off < 16; off <<= 1) {
#pragma unroll
        for (int r = 0; r < 4; ++r) {
            const float ob  = __shfl_xor(best[r],  off, 64);
            const float ob2 = __shfl_xor(best2[r], off, 64);
            const int   oi  = __shfl_xor(bidx[r],  off, 64);
            const float nb2 = fminf(fminf(best2[r], ob2), fmaxf(best[r], ob));
            if (ob < best[r]) { best[r] = ob; bidx[r] = oi; }
            best2[r] = nb2;
        }
    }

    if (col == 0) {
#pragma unroll
        for (int r = 0; r < 4; ++r) {
            const int n0 = pbase + quad * 4 + r;
            idx_ws[n0] = bidx[r];
            ind_out[n0] = (float)bidx[r];
            if (best2[r] - best[r] < MARGIN_TH) {
                const int pos = atomicAdd(nflag, 1);
                flags[pos] = n0;
            }
        }
    }
}

// ---------------- K1c: fp64 exact rescan for near-tie points (wave per point) ----------------
__global__ __launch_bounds__(256) void vq_fallback(
    const float* __restrict__ z, const float* __restrict__ emb,
    int* __restrict__ idx_ws, float* __restrict__ ind_out,
    const int* __restrict__ nflag, const int* __restrict__ flags)
{
    __shared__ float zs[4][DD];
    const int total = *nflag;
    const int lane = threadIdx.x & 63;
    const int wid = threadIdx.x >> 6;
    const int gw = blockIdx.x * 4 + wid;

    for (int i = gw; i < total; i += gridDim.x * 4) {
        const int n = flags[i];
        const int b = n >> 12, t = n & 4095;
        zs[wid][lane] = z[((size_t)b * DD + lane) * TD + t];
        __builtin_amdgcn_s_waitcnt(0);
        double best = 1e300;
        int bi = KK;
        for (int kc = 0; kc < KK / 64; ++kc) {
            const int k = kc * 64 + lane;
            const float4* e = (const float4*)(emb + (size_t)k * DD);
            double dot = 0.0, nn = 0.0;
#pragma unroll
            for (int j = 0; j < 16; ++j) {
                float4 ev = e[j];
                double e0 = (double)ev.x, e1 = (double)ev.y, e2 = (double)ev.z, e3 = (double)ev.w;
                nn = fma(e0, e0, fma(e1, e1, fma(e2, e2, fma(e3, e3, nn))));
                dot = fma((double)zs[wid][4 * j + 0], e0,
                      fma((double)zs[wid][4 * j + 1], e1,
                      fma((double)zs[wid][4 * j + 2], e2,
                      fma((double)zs[wid][4 * j + 3], e3, dot))));
            }
            double s = 0.5 * nn - dot;
            if (s < best || (s == best && k < bi)) { best = s; bi = k; }
        }
        for (int off = 32; off > 0; off >>= 1) {
            double os = __shfl_down(best, off, 64);
            int oi = __shfl_down(bi, off, 64);
            if (os < best || (os == best && oi < bi)) { best = os; bi = oi; }
        }
        if (lane == 0) { idx_ws[n] = bi; ind_out[n] = (float)bi; }
    }
}

// ---------------- K2a: histogram of final indices (LDS-privatized) ----------------
__global__ __launch_bounds__(256) void vq_hist(const int* __restrict__ idx_ws, int* __restrict__ hist)
{
    __shared__ int h[KK];
    for (int i = threadIdx.x; i < KK; i += 256) h[i] = 0;
    __syncthreads();
    const int base = blockIdx.x * 2048;
#pragma unroll
    for (int j = 0; j < 8; ++j)
        atomicAdd(&h[idx_ws[base + j * 256 + threadIdx.x]], 1);
    __syncthreads();
    for (int i = threadIdx.x; i < KK; i += 256)
        if (h[i]) atomicAdd(&hist[i], h[i]);
}

// ---------------- K2b: exclusive scan -> cursor, plus Laplace smoothing -> rsmo ----------------
__global__ __launch_bounds__(1024) void vq_prefix_smo(
    const int* __restrict__ hist, const float* __restrict__ cs,
    int* __restrict__ cursor, float* __restrict__ rsmo)
{
    __shared__ int tmp[KK];
    __shared__ double dred[KK];
    const int k = threadIdx.x;
    const int c = hist[k];
    tmp[k] = c;
    const double ncs = 0.99 * (double)cs[k] + 0.01 * (double)c;
    dred[k] = ncs;
    __syncthreads();
    for (int off = 1; off < KK; off <<= 1) {
        int u = (k >= off) ? tmp[k - off] : 0;
        __syncthreads();
        tmp[k] += u;
        __syncthreads();
    }
    cursor[k] = tmp[k] - c;  // exclusive
    for (int s = 512; s > 0; s >>= 1) {
        if (k < s) dred[k] += dred[k + s];
        __syncthreads();
    }
    const double nsum = dred[0];
    const double smo = (ncs + 1e-5) / (nsum + (double)KK * 1e-5) * nsum;
    rsmo[k] = (float)(1.0 / smo);
}

// ---------------- K2c: scatter point ids into per-code lists ----------------
__global__ __launch_bounds__(256) void vq_scatter(const int* __restrict__ idx_ws,
                                                  int* __restrict__ cursor, int* __restrict__ order)
{
    const int n = blockIdx.x * 256 + threadIdx.x;
    const int bi = idx_ws[n];
    const int pos = atomicAdd(&cursor[bi], 1);
    order[pos] = n;
}

// ---------------- K2d: balanced segment sum (zh/zl hold -z -> negate at flush) ----------------
__global__ __launch_bounds__(256) void vq_esum2(
    const unsigned short* __restrict__ zh, const unsigned short* __restrict__ zl,
    const int* __restrict__ idx_ws, const int* __restrict__ order,
    float* __restrict__ esum)
{
    const int tid = threadIdx.x;
    const int lane = tid & 63;
    const int w = tid >> 6;
    const int base = blockIdx.x * 256 + w * 64;   // this wave's 64 sorted positions

    const int pid_l = order[base + lane];          // coalesced
    const int code_l = idx_ws[pid_l];              // gather (one per lane)

    float v[64];
#pragma unroll
    for (int j = 0; j < 64; ++j) {
        const int pj = __shfl(pid_l, j, 64);
        const size_t o = (size_t)pj * DD + lane;   // 128 B coalesced per row
        v[j] = bf2f(zh[o]) + bf2f(zl[o]);
    }

    float racc = 0.f;
    int cur = __shfl(code_l, 0, 64);
#pragma unroll
    for (int j = 0; j < 64; ++j) {
        const int cj = __shfl(code_l, j, 64);      // wave-uniform
        if (cj != cur) {
            atomicAdd(&esum[(size_t)cur * DD + lane], -racc);
            racc = 0.f;
            cur = cj;
        }
        racc += v[j];
    }
    atomicAdd(&esum[(size_t)cur * DD + lane], -racc);
}

// ---------------- K3: new embedding (parallel) ----------------
__global__ __launch_bounds__(256) void vq_newE(
    const float* __restrict__ avg, const float* __restrict__ esum,
    const float* __restrict__ rsmo, float* __restrict__ newE)
{
    const int j = blockIdx.x * 256 + threadIdx.x;   // 65536 total
    newE[j] = (float)((0.99 * (double)avg[j] + 0.01 * (double)esum[j]) * (double)rsmo[j >> 6]);
}

// ---------------- K4: gather z_q + commitment loss (finalize fused) ----------------
__global__ __launch_bounds__(256) void vq_gather_loss(
    const float* __restrict__ z, const float* __restrict__ newE,
    const int* __restrict__ idx_ws, float* __restrict__ zq_out,
    double* __restrict__ loss_acc, int* __restrict__ done_cnt,
    float* __restrict__ loss_out)
{
    const int tid = threadIdx.x;
    const int n = blockIdx.x * 256 + tid;
    const int b = n >> 12;
    const int t = n & 4095;
    const float* zb = z + ((size_t)b * DD) * TD + t;
    float* ob = zq_out + ((size_t)b * DD) * TD + t;
    const int bi = idx_ws[n];
    const float* e = newE + (size_t)bi * DD;
    double acc = 0.0;
#pragma unroll
    for (int d = 0; d < DD; ++d) {
        float q = e[d];
        float zv = zb[(size_t)d * TD];
        ob[(size_t)d * TD] = q;
        float df = zv - q;
        acc = fma((double)df, (double)df, acc);
    }
    for (int off = 32; off > 0; off >>= 1) acc += __shfl_down(acc, off, 64);
    __shared__ double wsum[4];
    const int wid = tid >> 6, lane = tid & 63;
    if (lane == 0) wsum[wid] = acc;
    __syncthreads();
    if (tid == 0) {
        atomicAdd(loss_acc, wsum[0] + wsum[1] + wsum[2] + wsum[3]);
        __threadfence();
        const int prev = atomicAdd(done_cnt, 1);
        if (prev == gridDim.x - 1) {
            __threadfence();
            *loss_out = (float)(0.25 * (*loss_acc) / (double)(N_PTS * DD));
        }
    }
}

extern "C" void kernel_launch(void* const* d_in, const int* in_sizes, int n_in,
                              void* d_out, int out_size, void* d_ws, size_t ws_size,
                              hipStream_t stream) {
    const float* z    = (const float*)d_in[0];   // [32, 64, 4096]
    const float* emb  = (const float*)d_in[1];   // [1024, 64]
    const float* cs   = (const float*)d_in[2];   // [1024]
    const float* avg  = (const float*)d_in[3];   // [1024, 64]

    float* out      = (float*)d_out;
    float* zq_out   = out;                // 8388608 floats (32 MiB)
    float* loss_out = out + 8388608;      // 1
    float* ind_out  = out + 8388609;      // 131072 (indices as float)

    // z_hi/z_lo bf16 [N][D] exactly fill the z_q region (dead before K4 rewrites it)
    unsigned short* zh = (unsigned short*)d_out;                       // 16 MiB
    unsigned short* zl = (unsigned short*)((char*)d_out + 16777216);   // 16 MiB

    char* ws = (char*)d_ws;
    int*            idx_ws   = (int*)ws;                     // 512 KB @ 0
    float*          newE     = (float*)(ws + 524288);        // 256 KB
    float*          esum     = (float*)(ws + 786432);        // 256 KB [memset]
    int*            hist     = (int*)(ws + 1048576);         // 4 KB   [memset]
    int*            nflag    = (int*)(ws + 1052672);         // 4 B    [memset]
    int*            done_cnt = (int*)(ws + 1052676);         // 4 B    [memset]
    double*         loss_acc = (double*)(ws + 1052680);      // 8 B    [memset]
    float*          halfnorm = (float*)(ws + 1052688);       // 4 KB
    int*            cursor   = (int*)(ws + 1056784);         // 4 KB
    int*            flags    = (int*)(ws + 1060880);         // 512 KB
    int*            order    = (int*)(ws + 1585168);         // 512 KB
    unsigned short* efh      = (unsigned short*)(ws + 2109456); // 128 KB (fragment-ordered hi)
    unsigned short* efl      = (unsigned short*)(ws + 2240528); // 128 KB (fragment-ordered lo)
    float*          rsmo     = (float*)(ws + 2371600);       // 4 KB (end ~2.38 MB)

    // zero esum + hist + nflag + done_cnt + loss_acc (contiguous 786432..1052688)
    hipMemsetAsync(ws + 786432, 0, 266256, stream);

    vq_prep<<<2052, 256, 0, stream>>>(z, zh, zl, emb, efh, efl, halfnorm);
    vq_screen_mfma<<<N_PTS / 64, 256, 0, stream>>>(zh, zl, efh, efl, halfnorm,
                                                   idx_ws, ind_out, nflag, flags);
    vq_fallback<<<128, 256, 0, stream>>>(z, emb, idx_ws, ind_out, nflag, flags);
    vq_hist<<<64, 256, 0, stream>>>(idx_ws, hist);
    vq_prefix_smo<<<1, 1024, 0, stream>>>(hist, cs, cursor, rsmo);
    vq_scatter<<<N_PTS / 256, 256, 0, stream>>>(idx_ws, cursor, order);
    vq_esum2<<<N_PTS / 256, 256, 0, stream>>>(zh, zl, idx_ws, order, esum);
    vq_newE<<<256, 256, 0, stream>>>(avg, esum, rsmo, newE);
    vq_gather_loss<<<N_PTS / 256, 256, 0, stream>>>(z, newE, idx_ws, zq_out,
                                                    loss_acc, done_cnt, loss_out);
}